// Round 18
// baseline (109.441 us; speedup 1.0000x reference)
//
#include <hip/hip_runtime.h>
#include <cstdint>
#include <cstddef>

typedef __attribute__((ext_vector_type(8))) short bf16x8;
typedef __attribute__((ext_vector_type(4))) float f32x4;
typedef __attribute__((ext_vector_type(4))) unsigned short ushort4v;
typedef __attribute__((ext_vector_type(2))) unsigned int uint2v;

#define B_SZ   512
#define D1_IN  40
#define T_DIM  1024
#define D1_OUT 120
#define D2_OUT 64
#define OUT0_SZ (B_SZ * D1_OUT * D2_OUT) // 3932160

// per-bn bitmask of nonzero 32-wide k-steps of W (general sparsity skip)
__device__ unsigned int g_wmask[8];

// ---- helpers ----
__device__ __forceinline__ unsigned short f2bf(float f) {   // RNE
    unsigned int u = __float_as_uint(f);
    u += 0x7FFFu + ((u >> 16) & 1u);
    return (unsigned short)(u >> 16);
}
__device__ __forceinline__ void gld16v(const void* g, void* l) {
    __builtin_amdgcn_global_load_lds(
        (const __attribute__((address_space(1))) unsigned int*)g,
        (__attribute__((address_space(3))) unsigned int*)l, 16, 0, 0);
}

// ---- merged small prep: W2 swizzled re-layout (blocks 0..63), wmask (64..71), w1pad (72) ----
__global__ __launch_bounds__(256) void k_prep_small(const float* __restrict__ W1,
                                                    const float* __restrict__ W,
                                                    const float* __restrict__ W2,
                                                    unsigned short* __restrict__ w2g,
                                                    unsigned short* __restrict__ w1p) {
    int blk = blockIdx.x, tid = threadIdx.x;
    if (blk < 64) {
        __shared__ float tile[32][33];
        int c0 = (blk & 1) * 32, r0 = (blk >> 1) * 32;
        int tx = tid & 31, ty = tid >> 5;
        #pragma unroll
        for (int i = 0; i < 4; i++)
            tile[ty + i * 8][tx] = W2[(size_t)(r0 + ty + i * 8) * D2_OUT + c0 + tx];
        __syncthreads();
        #pragma unroll
        for (int i = 0; i < 4; i++) {
            int s = c0 + ty + i * 8;      // 0..63
            int t = r0 + tx;              // 0..1023
            size_t idx = ((size_t)(t >> 6) * 64 + s) * 64
                       + ((((t >> 3) & 7) ^ (s & 7)) << 3) + (t & 7);
            w2g[idx] = f2bf(tile[tx][ty + i * 8]);
        }
    } else if (blk < 72) {
        __shared__ unsigned int sm[256];
        int bn = blk - 64;
        int rbase = tid >> 5, c0 = (tid & 31) * 4;
        unsigned int m = 0;
        for (int ks = 0; ks < 32; ks++) {
            bool nz = false;
            #pragma unroll
            for (int i = 0; i < 4; i++) {
                int r = ks * 32 + rbase + i * 8;
                float4 v = *(const float4*)(W + (size_t)r * T_DIM + bn * 128 + c0);
                nz |= (v.x != 0.f) | (v.y != 0.f) | (v.z != 0.f) | (v.w != 0.f);
            }
            if (nz) m |= (1u << ks);
        }
        sm[tid] = m;
        __syncthreads();
        if (tid == 0) {
            unsigned int acc = 0;
            for (int i = 0; i < 256; i++) acc |= sm[i];
            g_wmask[bn] = acc;
        }
    } else {
        for (int i = tid; i < 128 * 64; i += 256) {
            int o = i >> 6, f = i & 63;
            w1p[i] = (o < D1_OUT && f < D1_IN) ? f2bf(W1[o * D1_IN + f]) : (unsigned short)0;
        }
    }
}

// ---- wfrag: W (1024x1024 fp32) -> MFMA-A-fragment-ordered bf16 ----
__global__ __launch_bounds__(256) void k_wfrag(const float* __restrict__ W,
                                               unsigned short* __restrict__ wfrag) {
    __shared__ float tl[32 * 132];
    int bn = blockIdx.x >> 5, ks = blockIdx.x & 31;
    int tid = threadIdx.x;
    int k0 = ks * 32, c0 = bn * 128;
    for (int i = tid; i < 1024; i += 256) {
        int r = i >> 5, c4 = i & 31;
        float4 v = *(const float4*)(W + (size_t)(k0 + r) * T_DIM + c0 + c4 * 4);
        *(float4*)&tl[r * 132 + c4 * 4] = v;
    }
    __syncthreads();
    int l = tid & 63, v = tid >> 6;      // 4 waves
    int rr = l & 15, q = l >> 4;
    #pragma unroll
    for (int nn = 0; nn < 2; nn++) {
        int n = v + nn * 4;
        bf16x8 o;
        #pragma unroll
        for (int j = 0; j < 8; j++)
            o[j] = (short)f2bf(tl[(q * 8 + j) * 132 + n * 16 + rr]);
        *(bf16x8*)(wfrag + (((size_t)(bn * 32 + ks) * 8 + n) * 512) + (size_t)l * 8) = o;
    }
}

// ---- GEMM1 + softmax fused (v8): A = softmax(x @ W, axis=1).
//      M=32 rows/block; masked K-loop SOFTWARE-PIPELINED: next active ks's x
//      fragments prefetched (branchless __ffs walk) so x latency hides under
//      the current step's wfrag loads + MFMAs. ----
__global__ __launch_bounds__(512) void k_gemm1sm(const float* __restrict__ x,
                                                 const unsigned short* __restrict__ wfrag,
                                                 float* __restrict__ A) {
    __shared__ float red[32][9];
    int row0 = blockIdx.x * 32;
    int tid = threadIdx.x, l = tid & 63, w = tid >> 6;
    int rr = l & 15, q = l >> 4;
    unsigned int mask = g_wmask[w];
    f32x4 acc[2][8] = {};
    const float* xrow0 = x + (size_t)(row0 + rr) * T_DIM;
    const float* xrow1 = x + (size_t)(row0 + 16 + rr) * T_DIM;

    auto LOADX = [&](int ks, bf16x8& o0, bf16x8& o1) {
        int off = ks * 32 + q * 8;
        f32x4 a0 = *(const f32x4*)(xrow0 + off);
        f32x4 b0 = *(const f32x4*)(xrow0 + off + 4);
        f32x4 a1 = *(const f32x4*)(xrow1 + off);
        f32x4 b1 = *(const f32x4*)(xrow1 + off + 4);
        ((unsigned int*)&o0)[0] = (__float_as_uint(a0.x) >> 16) | (__float_as_uint(a0.y) & 0xFFFF0000u);
        ((unsigned int*)&o0)[1] = (__float_as_uint(a0.z) >> 16) | (__float_as_uint(a0.w) & 0xFFFF0000u);
        ((unsigned int*)&o0)[2] = (__float_as_uint(b0.x) >> 16) | (__float_as_uint(b0.y) & 0xFFFF0000u);
        ((unsigned int*)&o0)[3] = (__float_as_uint(b0.z) >> 16) | (__float_as_uint(b0.w) & 0xFFFF0000u);
        ((unsigned int*)&o1)[0] = (__float_as_uint(a1.x) >> 16) | (__float_as_uint(a1.y) & 0xFFFF0000u);
        ((unsigned int*)&o1)[1] = (__float_as_uint(a1.z) >> 16) | (__float_as_uint(a1.w) & 0xFFFF0000u);
        ((unsigned int*)&o1)[2] = (__float_as_uint(b1.x) >> 16) | (__float_as_uint(b1.y) & 0xFFFF0000u);
        ((unsigned int*)&o1)[3] = (__float_as_uint(b1.z) >> 16) | (__float_as_uint(b1.w) & 0xFFFF0000u);
    };

    unsigned int mrem = mask;
    int ks = mrem ? (__ffs(mrem) - 1) : -1;
    mrem &= mrem - 1;
    bf16x8 c0, c1;
    if (ks >= 0) LOADX(ks, c0, c1);
    while (ks >= 0) {
        int ksn = mrem ? (__ffs(mrem) - 1) : -1;
        mrem &= mrem - 1;
        bf16x8 n0, n1;
        if (ksn >= 0) LOADX(ksn, n0, n1);     // issued before current MFMAs
        const unsigned short* wp = wfrag + ((size_t)(w * 32 + ks) * 8) * 512 + (size_t)l * 8;
        #pragma unroll
        for (int n = 0; n < 8; n++) {
            bf16x8 af = *(const bf16x8*)(wp + (size_t)n * 512);
            acc[0][n] = __builtin_amdgcn_mfma_f32_16x16x32_bf16(af, c0, acc[0][n], 0, 0, 0);
            acc[1][n] = __builtin_amdgcn_mfma_f32_16x16x32_bf16(af, c1, acc[1][n], 0, 0, 0);
        }
        c0 = n0; c1 = n1; ks = ksn;
    }

    // ---- softmax (per m-tile): lane (rr,q) holds E[row][w*128 + n*16 + q*4 + jj] ----
    #pragma unroll
    for (int m = 0; m < 2; m++) {
        float mx = -3.4e38f;
        #pragma unroll
        for (int n = 0; n < 8; n++)
            #pragma unroll
            for (int jj = 0; jj < 4; jj++) mx = fmaxf(mx, acc[m][n][jj]);
        mx = fmaxf(mx, __shfl_xor(mx, 16));
        mx = fmaxf(mx, __shfl_xor(mx, 32));
        if (l < 16) red[m * 16 + rr][w] = mx;
    }
    __syncthreads();
    float gm[2];
    #pragma unroll
    for (int m = 0; m < 2; m++) {
        float g = red[m * 16 + rr][0];
        #pragma unroll
        for (int ww = 1; ww < 8; ww++) g = fmaxf(g, red[m * 16 + rr][ww]);
        gm[m] = g;
    }
    __syncthreads();
    #pragma unroll
    for (int m = 0; m < 2; m++) {
        float s = 0.f;
        #pragma unroll
        for (int n = 0; n < 8; n++)
            #pragma unroll
            for (int jj = 0; jj < 4; jj++) {
                float p = __expf(acc[m][n][jj] - gm[m]);
                acc[m][n][jj] = p;
                s += p;
            }
        s += __shfl_xor(s, 16);
        s += __shfl_xor(s, 32);
        if (l < 16) red[m * 16 + rr][w] = s;
    }
    __syncthreads();
    #pragma unroll
    for (int m = 0; m < 2; m++) {
        float tot = 0.f;
        #pragma unroll
        for (int ww = 0; ww < 8; ww++) tot += red[m * 16 + rr][ww];
        float inv = 1.f / tot;
        size_t rowg = (size_t)(row0 + m * 16 + rr) * T_DIM + w * 128;
        #pragma unroll
        for (int n = 0; n < 8; n++) {
            f32x4 o;
            o.x = acc[m][n][0] * inv; o.y = acc[m][n][1] * inv;
            o.z = acc[m][n][2] * inv; o.w = acc[m][n][3] * inv;
            *(f32x4*)&A[rowg + n * 16 + q * 4] = o;
        }
    }
}

// ---- fused: stage x fp32 + gate (A fp32, L3-hot) via gld16v into group-padded LDS;
//      CONVERT x to bf16 [t][f]; MFMA1, fp32 gate, GEMM2, bias+relu. ----
__global__ __launch_bounds__(512) void k_fused(const float* __restrict__ x,
                                               const float* __restrict__ A,
                                               const unsigned short* __restrict__ w1p,
                                               const unsigned short* __restrict__ w2g,
                                               const float* __restrict__ Bias,
                                               const float* __restrict__ lamp,
                                               float* __restrict__ out) {
    __shared__ float xfst[2][10 * 260];           // x chunk fp32, group-padded  20800B
    __shared__ float gst[2][10 * 260];            // A chunk fp32, group-padded  20800B
    __shared__ unsigned short w2s[64 * 64];       // swizzled w2 chunk (single)   8192B
    __shared__ unsigned short xbt[64 * 72];       // x transposed bf16 [t][f]     9216B
    __shared__ unsigned short xtl[128 * 72];      // X_tilde [o][t]              18432B
    int b = blockIdx.x;
    int tid = threadIdx.x, l = tid & 63, w = tid >> 6;   // 8 waves
    int rr = l & 15, q = l >> 4;
    float lam = fminf(fmaxf(lamp[0], 0.f), 1.f), oml = 1.f - lam;
    bf16x8 aw[2];
    #pragma unroll
    for (int ks = 0; ks < 2; ks++)
        aw[ks] = *(const bf16x8*)(w1p + (w * 16 + rr) * 64 + ks * 32 + q * 8);
    int og = w * 16 + rr;              // lane's fixed o (strip row)
    int am = og % D1_IN;               // gate row
    int amg = (am >> 2) * 260 + (am & 3) * 64;    // group-padded base of gate row
    f32x4 acc2[4] = {};
    const float* xb = x + (size_t)b * D1_IN * T_DIM;
    const float* Ab = A + (size_t)b * D1_IN * T_DIM;

    auto STAGE_XG = [&](int buf, int tc) {
        int t0 = tc * 64;
        int f = w * 4 + (l >> 4);                 // group w: rows 4w..4w+3
        gld16v(xb + (size_t)f * T_DIM + t0 + (l & 15) * 4, &xfst[buf][w * 260]);
        gld16v(Ab + (size_t)f * T_DIM + t0 + (l & 15) * 4, &gst[buf][w * 260]);
        if (w < 2) {
            int f2 = 32 + w * 4 + (l >> 4);       // groups 8,9: rows 32..39
            gld16v(xb + (size_t)f2 * T_DIM + t0 + (l & 15) * 4, &xfst[buf][(8 + w) * 260]);
            gld16v(Ab + (size_t)f2 * T_DIM + t0 + (l & 15) * 4, &gst[buf][(8 + w) * 260]);
        }
    };
    auto STAGE_W2 = [&](int tc) {
        gld16v(w2g + (size_t)tc * 4096 + w * 512 + l * 8, &w2s[w * 512]);
    };
    // transpose-convert xfst[buf] fp32 [f][t] -> xbt bf16 [t][f]; 320 threads
    auto CONVERT = [&](int buf) {
        if (tid < 320) {
            int g = tid >> 5, tp = tid & 31;      // g = f-quad 0..9, tp = t-pair
            const float* src = &xfst[buf][g * 260 + 2 * tp];
            float a0 = src[0],   b0 = src[1];
            float a1 = src[64],  b1 = src[65];
            float a2 = src[128], b2 = src[129];
            float a3 = src[192], b3 = src[193];
            uint2v lo, hi;
            lo.x = (unsigned int)f2bf(a0) | ((unsigned int)f2bf(a1) << 16);
            lo.y = (unsigned int)f2bf(a2) | ((unsigned int)f2bf(a3) << 16);
            hi.x = (unsigned int)f2bf(b0) | ((unsigned int)f2bf(b1) << 16);
            hi.y = (unsigned int)f2bf(b2) | ((unsigned int)f2bf(b3) << 16);
            int t = 2 * tp;
            *(uint2v*)&xbt[t * 72 + g * 4] = lo;
            *(uint2v*)&xbt[(t + 1) * 72 + g * 4] = hi;
        }
    };

    // zero the f>=40 region of xbt once (stays zero; W1 pad rows are zero too)
    {
        int t = tid >> 3, k = tid & 7;
        *(uint2v*)&xbt[t * 72 + 40 + k * 4] = (uint2v){0u, 0u};   // covers f 40..71
    }
    STAGE_XG(0, 0);
    __syncthreads();
    for (int tc = 0; tc < 16; tc++) {
        int cur = tc & 1;
        CONVERT(cur);
        STAGE_W2(tc);
        __syncthreads();                       // A: xbt + w2s ready (vmcnt drained)
        if (tc < 15) STAGE_XG(cur ^ 1, tc + 1);  // prefetch overlaps compute
        // X_bar^T via MFMA: D[t][o], lane holds t = ni*16 + q*4+j at fixed o = og
        f32x4 acc1[4] = {};
        #pragma unroll
        for (int ni = 0; ni < 4; ni++)
            #pragma unroll
            for (int ks = 0; ks < 2; ks++) {
                bf16x8 bx = *(const bf16x8*)&xbt[(ni * 16 + rr) * 72 + ks * 32 + q * 8];
                acc1[ni] = __builtin_amdgcn_mfma_f32_16x16x32_bf16(bx, aw[ks], acc1[ni], 0, 0, 0);
            }
        // gate (fp32 LDS, lane-fixed row am) + pack -> one ds_write_b64 per ni
        const float* gr = &gst[cur][amg];
        #pragma unroll
        for (int ni = 0; ni < 4; ni++) {
            f32x4 gv = *(const f32x4*)(gr + ni * 16 + q * 4);
            float e0 = acc1[ni][0] * (lam * gv.x + oml);
            float e1 = acc1[ni][1] * (lam * gv.y + oml);
            float e2 = acc1[ni][2] * (lam * gv.z + oml);
            float e3 = acc1[ni][3] * (lam * gv.w + oml);
            uint2 pk;
            pk.x = (unsigned int)f2bf(e0) | ((unsigned int)f2bf(e1) << 16);
            pk.y = (unsigned int)f2bf(e2) | ((unsigned int)f2bf(e3) << 16);
            *(uint2*)&xtl[og * 72 + ni * 16 + q * 4] = pk;
        }
        // GEMM2: a2 row = og (same-wave RAW on xtl), b2 from swizzled w2s LDS
        #pragma unroll
        for (int ks2 = 0; ks2 < 2; ks2++) {
            bf16x8 a2 = *(const bf16x8*)&xtl[og * 72 + ks2 * 32 + q * 8];
            #pragma unroll
            for (int ni = 0; ni < 4; ni++) {
                int s = ni * 16 + rr;
                bf16x8 b2 = *(const bf16x8*)&w2s[s * 64 + (((ks2 * 4 + q) ^ (s & 7)) << 3)];
                acc2[ni] = __builtin_amdgcn_mfma_f32_16x16x32_bf16(a2, b2, acc2[ni], 0, 0, 0);
            }
        }
        __syncthreads();                       // B: drains prefetch; protects buffers
    }
    #pragma unroll
    for (int ni = 0; ni < 4; ni++)
        #pragma unroll
        for (int j = 0; j < 4; j++) {
            int row = w * 16 + q * 4 + j;
            if (row < D1_OUT) {
                int col = ni * 16 + rr;
                float v = acc2[ni][j] + Bias[row * D2_OUT + col];
                out[((size_t)b * D1_OUT + row) * D2_OUT + col] = fmaxf(v, 0.f);
            }
        }
}

extern "C" void kernel_launch(void* const* d_in, const int* in_sizes, int n_in,
                              void* d_out, int out_size, void* d_ws, size_t ws_size,
                              hipStream_t stream) {
    const float* x    = (const float*)d_in[0];
    const float* W1   = (const float*)d_in[1];
    const float* W    = (const float*)d_in[2];
    const float* W2   = (const float*)d_in[3];
    const float* Bias = (const float*)d_in[4];
    const float* lam  = (const float*)d_in[5];
    float* out = (float*)d_out;
    float* A   = out + OUT0_SZ;                    // second output region

    char* ws = (char*)d_ws;
    unsigned short* wfrag = (unsigned short*)(ws);              // 2 MB
    unsigned short* w2g   = (unsigned short*)(ws + 2097152);    // 128 KB
    unsigned short* w1p   = (unsigned short*)(ws + 2228224);    // 16 KB (total ~2.25 MB)

    hipLaunchKernelGGL(k_prep_small, dim3(73), dim3(256), 0, stream, W1, W, W2, w2g, w1p);
    hipLaunchKernelGGL(k_wfrag, dim3(256), dim3(256), 0, stream, W, wfrag);
    hipLaunchKernelGGL(k_gemm1sm, dim3(640), dim3(512), 0, stream, x, wfrag, A);
    hipLaunchKernelGGL(k_fused, dim3(512), dim3(512), 0, stream, x, A, w1p, w2g, Bias, lam, out);
}

// Round 19
// 101.143 us; speedup vs baseline: 1.0820x; 1.0820x over previous
//
#include <hip/hip_runtime.h>
#include <cstdint>
#include <cstddef>

typedef __attribute__((ext_vector_type(8))) short bf16x8;
typedef __attribute__((ext_vector_type(4))) float f32x4;
typedef __attribute__((ext_vector_type(4))) unsigned short ushort4v;
typedef __attribute__((ext_vector_type(2))) unsigned int uint2v;

#define B_SZ   512
#define D1_IN  40
#define T_DIM  1024
#define D1_OUT 120
#define D2_OUT 64
#define OUT0_SZ (B_SZ * D1_OUT * D2_OUT) // 3932160

// per-bn bitmask of nonzero 32-wide k-steps of W (general sparsity skip)
__device__ unsigned int g_wmask[8];

// ---- helpers ----
__device__ __forceinline__ unsigned short f2bf(float f) {   // RNE
    unsigned int u = __float_as_uint(f);
    u += 0x7FFFu + ((u >> 16) & 1u);
    return (unsigned short)(u >> 16);
}
__device__ __forceinline__ float bf2f(unsigned int h) {
    return __uint_as_float(h << 16);
}
__device__ __forceinline__ void gld16v(const void* g, void* l) {
    __builtin_amdgcn_global_load_lds(
        (const __attribute__((address_space(1))) unsigned int*)g,
        (__attribute__((address_space(3))) unsigned int*)l, 16, 0, 0);
}

// ---- merged small prep: W2 swizzled re-layout (blocks 0..63), wmask (64..71), w1pad (72) ----
__global__ __launch_bounds__(256) void k_prep_small(const float* __restrict__ W1,
                                                    const float* __restrict__ W,
                                                    const float* __restrict__ W2,
                                                    unsigned short* __restrict__ w2g,
                                                    unsigned short* __restrict__ w1p) {
    int blk = blockIdx.x, tid = threadIdx.x;
    if (blk < 64) {
        __shared__ float tile[32][33];
        int c0 = (blk & 1) * 32, r0 = (blk >> 1) * 32;
        int tx = tid & 31, ty = tid >> 5;
        #pragma unroll
        for (int i = 0; i < 4; i++)
            tile[ty + i * 8][tx] = W2[(size_t)(r0 + ty + i * 8) * D2_OUT + c0 + tx];
        __syncthreads();
        #pragma unroll
        for (int i = 0; i < 4; i++) {
            int s = c0 + ty + i * 8;      // 0..63
            int t = r0 + tx;              // 0..1023
            size_t idx = ((size_t)(t >> 6) * 64 + s) * 64
                       + ((((t >> 3) & 7) ^ (s & 7)) << 3) + (t & 7);
            w2g[idx] = f2bf(tile[tx][ty + i * 8]);
        }
    } else if (blk < 72) {
        __shared__ unsigned int sm[256];
        int bn = blk - 64;
        int rbase = tid >> 5, c0 = (tid & 31) * 4;
        unsigned int m = 0;
        for (int ks = 0; ks < 32; ks++) {
            bool nz = false;
            #pragma unroll
            for (int i = 0; i < 4; i++) {
                int r = ks * 32 + rbase + i * 8;
                float4 v = *(const float4*)(W + (size_t)r * T_DIM + bn * 128 + c0);
                nz |= (v.x != 0.f) | (v.y != 0.f) | (v.z != 0.f) | (v.w != 0.f);
            }
            if (nz) m |= (1u << ks);
        }
        sm[tid] = m;
        __syncthreads();
        if (tid == 0) {
            unsigned int acc = 0;
            for (int i = 0; i < 256; i++) acc |= sm[i];
            g_wmask[bn] = acc;
        }
    } else {
        for (int i = tid; i < 128 * 64; i += 256) {
            int o = i >> 6, f = i & 63;
            w1p[i] = (o < D1_OUT && f < D1_IN) ? f2bf(W1[o * D1_IN + f]) : (unsigned short)0;
        }
    }
}

// ---- wfrag: W (1024x1024 fp32) -> MFMA-A-fragment-ordered bf16 ----
__global__ __launch_bounds__(256) void k_wfrag(const float* __restrict__ W,
                                               unsigned short* __restrict__ wfrag) {
    __shared__ float tl[32 * 132];
    int bn = blockIdx.x >> 5, ks = blockIdx.x & 31;
    int tid = threadIdx.x;
    int k0 = ks * 32, c0 = bn * 128;
    for (int i = tid; i < 1024; i += 256) {
        int r = i >> 5, c4 = i & 31;
        float4 v = *(const float4*)(W + (size_t)(k0 + r) * T_DIM + c0 + c4 * 4);
        *(float4*)&tl[r * 132 + c4 * 4] = v;
    }
    __syncthreads();
    int l = tid & 63, v = tid >> 6;      // 4 waves
    int rr = l & 15, q = l >> 4;
    #pragma unroll
    for (int nn = 0; nn < 2; nn++) {
        int n = v + nn * 4;
        bf16x8 o;
        #pragma unroll
        for (int j = 0; j < 8; j++)
            o[j] = (short)f2bf(tl[(q * 8 + j) * 132 + n * 16 + rr]);
        *(bf16x8*)(wfrag + (((size_t)(bn * 32 + ks) * 8 + n) * 512) + (size_t)l * 8) = o;
    }
}

// ---- MEGA: per-b block. Phase 1/2: E = x@W (masked), softmax -> A (output) +
//      gate bf16 -> global gbuf (chunk-major, L2-hot). Phase 3: fused MFMA1/gate/
//      GEMM2 re-reading x (L2-hot, same block just read it) + gate via gld16v. ----
__global__ __launch_bounds__(512) void k_mega(const float* __restrict__ x,
                                              const unsigned short* __restrict__ wfrag,
                                              const unsigned short* __restrict__ w1p,
                                              const unsigned short* __restrict__ w2g,
                                              const float* __restrict__ Bias,
                                              const float* __restrict__ lamp,
                                              float* __restrict__ A,
                                              unsigned short* __restrict__ gbuf,
                                              float* __restrict__ out) {
    __shared__ float xfst[2][10 * 260];           // x chunk fp32, group-padded  20800B
    __shared__ unsigned short gs16[2][5 * 528];   // gate chunk bf16             10560B
    __shared__ unsigned short w2s[64 * 64];       // swizzled w2 chunk            8192B
    __shared__ unsigned short xbt[64 * 72];       // x transposed bf16 [t][f]     9216B
    __shared__ unsigned short xtl[128 * 72];      // X_tilde [o][t]              18432B
    __shared__ float red[32][9];                  //                              1152B
    int b = blockIdx.x;
    int tid = threadIdx.x, l = tid & 63, w = tid >> 6;   // 8 waves
    int rr = l & 15, q = l >> 4;
    float lam = fminf(fmaxf(lamp[0], 0.f), 1.f), oml = 1.f - lam;
    unsigned int mask = g_wmask[w];
    unsigned short* gb = gbuf + (size_t)b * 16 * 2560;   // [tc][f*64+tl] bf16

    // ================= PHASE 1/2 =================
    // helper: make bf16 fragment from a global x row at k-offset
    auto MKFRAG = [&](const float* xrow, int off, bf16x8& o) {
        f32x4 a0 = *(const f32x4*)(xrow + off);
        f32x4 b0 = *(const f32x4*)(xrow + off + 4);
        ((unsigned int*)&o)[0] = (__float_as_uint(a0.x) >> 16) | (__float_as_uint(a0.y) & 0xFFFF0000u);
        ((unsigned int*)&o)[1] = (__float_as_uint(a0.z) >> 16) | (__float_as_uint(a0.w) & 0xFFFF0000u);
        ((unsigned int*)&o)[2] = (__float_as_uint(b0.x) >> 16) | (__float_as_uint(b0.y) & 0xFFFF0000u);
        ((unsigned int*)&o)[3] = (__float_as_uint(b0.z) >> 16) | (__float_as_uint(b0.w) & 0xFFFF0000u);
    };
    auto SOFTMAX_STORE = [&](f32x4* acc, int m, bool valid) {
        // acc[n]: lane (rr,q) holds E[row][w*128+n*16+q*4+jj]; red row = m*16+rr
        float mx = -3.4e38f;
        #pragma unroll
        for (int n = 0; n < 8; n++)
            #pragma unroll
            for (int jj = 0; jj < 4; jj++) mx = fmaxf(mx, acc[n][jj]);
        mx = fmaxf(mx, __shfl_xor(mx, 16));
        mx = fmaxf(mx, __shfl_xor(mx, 32));
        if (l < 16) red[m * 16 + rr][w] = mx;
    };

    {
        // ---- group A: rows b*40 + {0..31} (2 m-tiles) ----
        const float* xrow0 = x + (size_t)(b * 40 + rr) * T_DIM;
        const float* xrow1 = x + (size_t)(b * 40 + 16 + rr) * T_DIM;
        f32x4 acc[2][8] = {};
        for (int ks = 0; ks < 32; ks++) {
            if (!((mask >> ks) & 1u)) continue;
            int off = ks * 32 + q * 8;
            bf16x8 bx0, bx1;
            MKFRAG(xrow0, off, bx0);
            MKFRAG(xrow1, off, bx1);
            const unsigned short* wp = wfrag + ((size_t)(w * 32 + ks) * 8) * 512 + (size_t)l * 8;
            #pragma unroll
            for (int n = 0; n < 8; n++) {
                bf16x8 af = *(const bf16x8*)(wp + (size_t)n * 512);
                acc[0][n] = __builtin_amdgcn_mfma_f32_16x16x32_bf16(af, bx0, acc[0][n], 0, 0, 0);
                acc[1][n] = __builtin_amdgcn_mfma_f32_16x16x32_bf16(af, bx1, acc[1][n], 0, 0, 0);
            }
        }
        #pragma unroll
        for (int m = 0; m < 2; m++) SOFTMAX_STORE(acc[m], m, true);
        __syncthreads();
        float gm[2];
        #pragma unroll
        for (int m = 0; m < 2; m++) {
            float g = red[m * 16 + rr][0];
            #pragma unroll
            for (int ww = 1; ww < 8; ww++) g = fmaxf(g, red[m * 16 + rr][ww]);
            gm[m] = g;
        }
        __syncthreads();
        #pragma unroll
        for (int m = 0; m < 2; m++) {
            float s = 0.f;
            #pragma unroll
            for (int n = 0; n < 8; n++)
                #pragma unroll
                for (int jj = 0; jj < 4; jj++) {
                    float p = __expf(acc[m][n][jj] - gm[m]);
                    acc[m][n][jj] = p;
                    s += p;
                }
            s += __shfl_xor(s, 16);
            s += __shfl_xor(s, 32);
            if (l < 16) red[m * 16 + rr][w] = s;
        }
        __syncthreads();
        #pragma unroll
        for (int m = 0; m < 2; m++) {
            float tot = 0.f;
            #pragma unroll
            for (int ww = 0; ww < 8; ww++) tot += red[m * 16 + rr][ww];
            float inv = 1.f / tot;
            int f = m * 16 + rr;                       // 0..31
            size_t rowg = (size_t)(b * 40 + f) * T_DIM + w * 128;
            #pragma unroll
            for (int n = 0; n < 8; n++) {
                f32x4 o;
                o.x = acc[m][n][0] * inv; o.y = acc[m][n][1] * inv;
                o.z = acc[m][n][2] * inv; o.w = acc[m][n][3] * inv;
                *(f32x4*)&A[rowg + n * 16 + q * 4] = o;
                uint2v pk;
                pk.x = (unsigned int)f2bf(lam * o.x + oml) | ((unsigned int)f2bf(lam * o.y + oml) << 16);
                pk.y = (unsigned int)f2bf(lam * o.z + oml) | ((unsigned int)f2bf(lam * o.w + oml) << 16);
                *(uint2v*)&gb[(size_t)(w * 2 + (n >> 2)) * 2560 + f * 64 + (n & 3) * 16 + q * 4] = pk;
            }
        }
        __syncthreads();                               // red reuse fence
    }
    {
        // ---- group B: rows b*40 + {32..39} (1 m-tile, rr<8 valid) ----
        int rowa = b * 40 + 32 + rr;
        int rowc = rowa < 20480 ? rowa : 20479;        // clamp (b=511, rr>=8)
        const float* xrowB = x + (size_t)rowc * T_DIM;
        f32x4 acc[8] = {};
        for (int ks = 0; ks < 32; ks++) {
            if (!((mask >> ks) & 1u)) continue;
            int off = ks * 32 + q * 8;
            bf16x8 bxB;
            MKFRAG(xrowB, off, bxB);
            const unsigned short* wp = wfrag + ((size_t)(w * 32 + ks) * 8) * 512 + (size_t)l * 8;
            #pragma unroll
            for (int n = 0; n < 8; n++) {
                bf16x8 af = *(const bf16x8*)(wp + (size_t)n * 512);
                acc[n] = __builtin_amdgcn_mfma_f32_16x16x32_bf16(af, bxB, acc[n], 0, 0, 0);
            }
        }
        float mx = -3.4e38f;
        #pragma unroll
        for (int n = 0; n < 8; n++)
            #pragma unroll
            for (int jj = 0; jj < 4; jj++) mx = fmaxf(mx, acc[n][jj]);
        mx = fmaxf(mx, __shfl_xor(mx, 16));
        mx = fmaxf(mx, __shfl_xor(mx, 32));
        if (l < 16) red[rr][w] = mx;
        __syncthreads();
        float g = red[rr][0];
        #pragma unroll
        for (int ww = 1; ww < 8; ww++) g = fmaxf(g, red[rr][ww]);
        __syncthreads();
        float s = 0.f;
        #pragma unroll
        for (int n = 0; n < 8; n++)
            #pragma unroll
            for (int jj = 0; jj < 4; jj++) {
                float p = __expf(acc[n][jj] - g);
                acc[n][jj] = p;
                s += p;
            }
        s += __shfl_xor(s, 16);
        s += __shfl_xor(s, 32);
        if (l < 16) red[rr][w] = s;
        __syncthreads();
        if (rr < 8) {
            float tot = 0.f;
            #pragma unroll
            for (int ww = 0; ww < 8; ww++) tot += red[rr][ww];
            float inv = 1.f / tot;
            int f = 32 + rr;
            size_t rowg = (size_t)(b * 40 + f) * T_DIM + w * 128;
            #pragma unroll
            for (int n = 0; n < 8; n++) {
                f32x4 o;
                o.x = acc[n][0] * inv; o.y = acc[n][1] * inv;
                o.z = acc[n][2] * inv; o.w = acc[n][3] * inv;
                *(f32x4*)&A[rowg + n * 16 + q * 4] = o;
                uint2v pk;
                pk.x = (unsigned int)f2bf(lam * o.x + oml) | ((unsigned int)f2bf(lam * o.y + oml) << 16);
                pk.y = (unsigned int)f2bf(lam * o.z + oml) | ((unsigned int)f2bf(lam * o.w + oml) << 16);
                *(uint2v*)&gb[(size_t)(w * 2 + (n >> 2)) * 2560 + f * 64 + (n & 3) * 16 + q * 4] = pk;
            }
        }
    }
    __syncthreads();   // all A + gate stores drained (vmcnt) before phase 3 reads gb

    // ================= PHASE 3 (fused) =================
    bf16x8 aw[2];
    #pragma unroll
    for (int ks = 0; ks < 2; ks++)
        aw[ks] = *(const bf16x8*)(w1p + (w * 16 + rr) * 64 + ks * 32 + q * 8);
    int og = w * 16 + rr;              // lane's fixed o (strip row)
    int am = og % D1_IN;               // gate row
    int gofs = (am >> 3) * 528 + (am & 7) * 64;
    f32x4 acc2[4] = {};
    const float* xb = x + (size_t)b * D1_IN * T_DIM;

    auto STAGE_XG = [&](int buf, int tc) {
        int t0 = tc * 64;
        int f = w * 4 + (l >> 4);                 // group w: x rows 4w..4w+3
        gld16v(xb + (size_t)f * T_DIM + t0 + (l & 15) * 4, &xfst[buf][w * 260]);
        if (w < 2) {
            int f2 = 32 + w * 4 + (l >> 4);       // groups 8,9: rows 32..39
            gld16v(xb + (size_t)f2 * T_DIM + t0 + (l & 15) * 4, &xfst[buf][(8 + w) * 260]);
        }
        if (w < 5)                                 // gate: 5 sgroups of 8 rows
            gld16v(gb + (size_t)tc * 2560 + w * 512 + l * 8, &gs16[buf][w * 528]);
    };
    auto STAGE_W2 = [&](int tc) {
        gld16v(w2g + (size_t)tc * 4096 + w * 512 + l * 8, &w2s[w * 512]);
    };
    auto CONVERT = [&](int buf) {
        if (tid < 320) {
            int g = tid >> 5, tp = tid & 31;      // g = f-quad 0..9, tp = t-pair
            const float* src = &xfst[buf][g * 260 + 2 * tp];
            float a0 = src[0],   b0 = src[1];
            float a1 = src[64],  b1 = src[65];
            float a2 = src[128], b2 = src[129];
            float a3 = src[192], b3 = src[193];
            uint2v lo, hi;
            lo.x = (unsigned int)f2bf(a0) | ((unsigned int)f2bf(a1) << 16);
            lo.y = (unsigned int)f2bf(a2) | ((unsigned int)f2bf(a3) << 16);
            hi.x = (unsigned int)f2bf(b0) | ((unsigned int)f2bf(b1) << 16);
            hi.y = (unsigned int)f2bf(b2) | ((unsigned int)f2bf(b3) << 16);
            int t = 2 * tp;
            *(uint2v*)&xbt[t * 72 + g * 4] = lo;
            *(uint2v*)&xbt[(t + 1) * 72 + g * 4] = hi;
        }
    };

    // zero the f>=40 region of xbt once (stays zero; W1 pad rows are zero too)
    {
        int t = tid >> 3, k = tid & 7;
        *(uint2v*)&xbt[t * 72 + 40 + k * 4] = (uint2v){0u, 0u};
    }
    STAGE_XG(0, 0);
    __syncthreads();
    for (int tc = 0; tc < 16; tc++) {
        int cur = tc & 1;
        CONVERT(cur);
        STAGE_W2(tc);
        __syncthreads();                       // A: xbt + gs16 + w2s ready
        if (tc < 15) STAGE_XG(cur ^ 1, tc + 1);  // prefetch overlaps compute
        // X_bar^T via MFMA: D[t][o], lane holds t = ni*16 + q*4+j at fixed o = og
        f32x4 acc1[4] = {};
        #pragma unroll
        for (int ni = 0; ni < 4; ni++)
            #pragma unroll
            for (int ks = 0; ks < 2; ks++) {
                bf16x8 bx = *(const bf16x8*)&xbt[(ni * 16 + rr) * 72 + ks * 32 + q * 8];
                acc1[ni] = __builtin_amdgcn_mfma_f32_16x16x32_bf16(bx, aw[ks], acc1[ni], 0, 0, 0);
            }
        // gate (bf16 LDS, pre-folded lam) + pack -> one ds_write_b64 per ni
        const unsigned short* gr = &gs16[cur][gofs];
        #pragma unroll
        for (int ni = 0; ni < 4; ni++) {
            uint2 gp = *(const uint2*)(gr + ni * 16 + q * 4);
            float e0 = acc1[ni][0] * bf2f(gp.x & 0xFFFFu);
            float e1 = acc1[ni][1] * bf2f(gp.x >> 16);
            float e2 = acc1[ni][2] * bf2f(gp.y & 0xFFFFu);
            float e3 = acc1[ni][3] * bf2f(gp.y >> 16);
            uint2 pk;
            pk.x = (unsigned int)f2bf(e0) | ((unsigned int)f2bf(e1) << 16);
            pk.y = (unsigned int)f2bf(e2) | ((unsigned int)f2bf(e3) << 16);
            *(uint2*)&xtl[og * 72 + ni * 16 + q * 4] = pk;
        }
        // GEMM2: a2 row = og (same-wave RAW on xtl), b2 from swizzled w2s LDS
        #pragma unroll
        for (int ks2 = 0; ks2 < 2; ks2++) {
            bf16x8 a2 = *(const bf16x8*)&xtl[og * 72 + ks2 * 32 + q * 8];
            #pragma unroll
            for (int ni = 0; ni < 4; ni++) {
                int s = ni * 16 + rr;
                bf16x8 b2 = *(const bf16x8*)&w2s[s * 64 + (((ks2 * 4 + q) ^ (s & 7)) << 3)];
                acc2[ni] = __builtin_amdgcn_mfma_f32_16x16x32_bf16(a2, b2, acc2[ni], 0, 0, 0);
            }
        }
        __syncthreads();                       // B: drains prefetch; protects buffers
    }
    #pragma unroll
    for (int ni = 0; ni < 4; ni++)
        #pragma unroll
        for (int j = 0; j < 4; j++) {
            int row = w * 16 + q * 4 + j;
            if (row < D1_OUT) {
                int col = ni * 16 + rr;
                float v = acc2[ni][j] + Bias[row * D2_OUT + col];
                out[((size_t)b * D1_OUT + row) * D2_OUT + col] = fmaxf(v, 0.f);
            }
        }
}

extern "C" void kernel_launch(void* const* d_in, const int* in_sizes, int n_in,
                              void* d_out, int out_size, void* d_ws, size_t ws_size,
                              hipStream_t stream) {
    const float* x    = (const float*)d_in[0];
    const float* W1   = (const float*)d_in[1];
    const float* W    = (const float*)d_in[2];
    const float* W2   = (const float*)d_in[3];
    const float* Bias = (const float*)d_in[4];
    const float* lam  = (const float*)d_in[5];
    float* out = (float*)d_out;
    float* A   = out + OUT0_SZ;                    // second output region

    char* ws = (char*)d_ws;
    unsigned short* gbuf  = (unsigned short*)(ws);              // 41,943,040 B
    unsigned short* wfrag = (unsigned short*)(ws + 41943040);   // 2 MB
    unsigned short* w2g   = (unsigned short*)(ws + 44040192);   // 128 KB
    unsigned short* w1p   = (unsigned short*)(ws + 44171264);   // 16 KB (total ~44.2 MB)

    hipLaunchKernelGGL(k_prep_small, dim3(73), dim3(256), 0, stream, W1, W, W2, w2g, w1p);
    hipLaunchKernelGGL(k_wfrag, dim3(256), dim3(256), 0, stream, W, wfrag);
    hipLaunchKernelGGL(k_mega, dim3(512), dim3(512), 0, stream, x, wfrag, w1p, w2g, Bias, lam, A, gbuf, out);
}

// Round 20
// 99.736 us; speedup vs baseline: 1.0973x; 1.0141x over previous
//
#include <hip/hip_runtime.h>
#include <cstdint>
#include <cstddef>

typedef __attribute__((ext_vector_type(8))) short bf16x8;
typedef __attribute__((ext_vector_type(4))) float f32x4;
typedef __attribute__((ext_vector_type(4))) unsigned short ushort4v;
typedef __attribute__((ext_vector_type(2))) unsigned int uint2v;
typedef __attribute__((ext_vector_type(4))) unsigned int uint4v;

#define B_SZ   512
#define D1_IN  40
#define T_DIM  1024
#define D1_OUT 120
#define D2_OUT 64
#define OUT0_SZ (B_SZ * D1_OUT * D2_OUT) // 3932160

// per-bn bitmask of nonzero 32-wide k-steps of W (general sparsity skip)
__device__ unsigned int g_wmask[8];

// ---- helpers ----
__device__ __forceinline__ unsigned short f2bf(float f) {   // RNE
    unsigned int u = __float_as_uint(f);
    u += 0x7FFFu + ((u >> 16) & 1u);
    return (unsigned short)(u >> 16);
}
__device__ __forceinline__ float bf2f(unsigned int h) {
    return __uint_as_float(h << 16);
}
__device__ __forceinline__ void gld16v(const void* g, void* l) {
    __builtin_amdgcn_global_load_lds(
        (const __attribute__((address_space(1))) unsigned int*)g,
        (__attribute__((address_space(3))) unsigned int*)l, 16, 0, 0);
}

// ---- merged small prep: W2 swizzled re-layout (blocks 0..63), wmask (64..71), w1pad (72) ----
__global__ __launch_bounds__(256) void k_prep_small(const float* __restrict__ W1,
                                                    const float* __restrict__ W,
                                                    const float* __restrict__ W2,
                                                    unsigned short* __restrict__ w2g,
                                                    unsigned short* __restrict__ w1p) {
    int blk = blockIdx.x, tid = threadIdx.x;
    if (blk < 64) {
        __shared__ float tile[32][33];
        int c0 = (blk & 1) * 32, r0 = (blk >> 1) * 32;
        int tx = tid & 31, ty = tid >> 5;
        #pragma unroll
        for (int i = 0; i < 4; i++)
            tile[ty + i * 8][tx] = W2[(size_t)(r0 + ty + i * 8) * D2_OUT + c0 + tx];
        __syncthreads();
        #pragma unroll
        for (int i = 0; i < 4; i++) {
            int s = c0 + ty + i * 8;      // 0..63
            int t = r0 + tx;              // 0..1023
            size_t idx = ((size_t)(t >> 6) * 64 + s) * 64
                       + ((((t >> 3) & 7) ^ (s & 7)) << 3) + (t & 7);
            w2g[idx] = f2bf(tile[tx][ty + i * 8]);
        }
    } else if (blk < 72) {
        __shared__ unsigned int sm[256];
        int bn = blk - 64;
        int rbase = tid >> 5, c0 = (tid & 31) * 4;
        unsigned int m = 0;
        for (int ks = 0; ks < 32; ks++) {
            bool nz = false;
            #pragma unroll
            for (int i = 0; i < 4; i++) {
                int r = ks * 32 + rbase + i * 8;
                float4 v = *(const float4*)(W + (size_t)r * T_DIM + bn * 128 + c0);
                nz |= (v.x != 0.f) | (v.y != 0.f) | (v.z != 0.f) | (v.w != 0.f);
            }
            if (nz) m |= (1u << ks);
        }
        sm[tid] = m;
        __syncthreads();
        if (tid == 0) {
            unsigned int acc = 0;
            for (int i = 0; i < 256; i++) acc |= sm[i];
            g_wmask[bn] = acc;
        }
    } else {
        for (int i = tid; i < 128 * 64; i += 256) {
            int o = i >> 6, f = i & 63;
            w1p[i] = (o < D1_OUT && f < D1_IN) ? f2bf(W1[o * D1_IN + f]) : (unsigned short)0;
        }
    }
}

// ---- wfrag: W (1024x1024 fp32) -> MFMA-A-fragment-ordered bf16 ----
__global__ __launch_bounds__(256) void k_wfrag(const float* __restrict__ W,
                                               unsigned short* __restrict__ wfrag) {
    __shared__ float tl[32 * 132];
    int bn = blockIdx.x >> 5, ks = blockIdx.x & 31;
    int tid = threadIdx.x;
    int k0 = ks * 32, c0 = bn * 128;
    for (int i = tid; i < 1024; i += 256) {
        int r = i >> 5, c4 = i & 31;
        float4 v = *(const float4*)(W + (size_t)(k0 + r) * T_DIM + c0 + c4 * 4);
        *(float4*)&tl[r * 132 + c4 * 4] = v;
    }
    __syncthreads();
    int l = tid & 63, v = tid >> 6;      // 4 waves
    int rr = l & 15, q = l >> 4;
    #pragma unroll
    for (int nn = 0; nn < 2; nn++) {
        int n = v + nn * 4;
        bf16x8 o;
        #pragma unroll
        for (int j = 0; j < 8; j++)
            o[j] = (short)f2bf(tl[(q * 8 + j) * 132 + n * 16 + rr]);
        *(bf16x8*)(wfrag + (((size_t)(bn * 32 + ks) * 8 + n) * 512) + (size_t)l * 8) = o;
    }
}

// ---- MEGA: per-b block. Phase 1/2: E = x@W (masked), softmax -> A (output) +
//      gate bf16 -> global gbuf (chunk-major, L2-hot). Phase 3: fused MFMA1/gate/
//      GEMM2; xbt is OCTET-XOR-SWIZZLED so CONVERT writes hit the b128 floor. ----
__global__ __launch_bounds__(512) void k_mega(const float* __restrict__ x,
                                              const unsigned short* __restrict__ wfrag,
                                              const unsigned short* __restrict__ w1p,
                                              const unsigned short* __restrict__ w2g,
                                              const float* __restrict__ Bias,
                                              const float* __restrict__ lamp,
                                              float* __restrict__ A,
                                              unsigned short* __restrict__ gbuf,
                                              float* __restrict__ out) {
    __shared__ float xfst[2][10 * 260];           // x chunk fp32, group-padded  20800B
    __shared__ unsigned short gs16[2][5 * 528];   // gate chunk bf16             10560B
    __shared__ unsigned short w2s[64 * 64];       // swizzled w2 chunk            8192B
    __shared__ unsigned short xbt[64 * 72];       // x [t][f] octet-swizzled      9216B
    __shared__ unsigned short xtl[128 * 72];      // X_tilde [o][t]              18432B
    __shared__ float red[32][9];                  //                              1152B
    int b = blockIdx.x;
    int tid = threadIdx.x, l = tid & 63, w = tid >> 6;   // 8 waves
    int rr = l & 15, q = l >> 4;
    float lam = fminf(fmaxf(lamp[0], 0.f), 1.f), oml = 1.f - lam;
    unsigned int mask = g_wmask[w];
    unsigned short* gb = gbuf + (size_t)b * 16 * 2560;   // [tc][f*64+tl] bf16

    // ================= PHASE 1/2 =================
    auto MKFRAG = [&](const float* xrow, int off, bf16x8& o) {
        f32x4 a0 = *(const f32x4*)(xrow + off);
        f32x4 b0 = *(const f32x4*)(xrow + off + 4);
        ((unsigned int*)&o)[0] = (__float_as_uint(a0.x) >> 16) | (__float_as_uint(a0.y) & 0xFFFF0000u);
        ((unsigned int*)&o)[1] = (__float_as_uint(a0.z) >> 16) | (__float_as_uint(a0.w) & 0xFFFF0000u);
        ((unsigned int*)&o)[2] = (__float_as_uint(b0.x) >> 16) | (__float_as_uint(b0.y) & 0xFFFF0000u);
        ((unsigned int*)&o)[3] = (__float_as_uint(b0.z) >> 16) | (__float_as_uint(b0.w) & 0xFFFF0000u);
    };

    {
        // ---- group A: rows b*40 + {0..31} (2 m-tiles) ----
        const float* xrow0 = x + (size_t)(b * 40 + rr) * T_DIM;
        const float* xrow1 = x + (size_t)(b * 40 + 16 + rr) * T_DIM;
        f32x4 acc[2][8] = {};
        for (int ks = 0; ks < 32; ks++) {
            if (!((mask >> ks) & 1u)) continue;
            int off = ks * 32 + q * 8;
            bf16x8 bx0, bx1;
            MKFRAG(xrow0, off, bx0);
            MKFRAG(xrow1, off, bx1);
            const unsigned short* wp = wfrag + ((size_t)(w * 32 + ks) * 8) * 512 + (size_t)l * 8;
            #pragma unroll
            for (int n = 0; n < 8; n++) {
                bf16x8 af = *(const bf16x8*)(wp + (size_t)n * 512);
                acc[0][n] = __builtin_amdgcn_mfma_f32_16x16x32_bf16(af, bx0, acc[0][n], 0, 0, 0);
                acc[1][n] = __builtin_amdgcn_mfma_f32_16x16x32_bf16(af, bx1, acc[1][n], 0, 0, 0);
            }
        }
        #pragma unroll
        for (int m = 0; m < 2; m++) {
            float mx = -3.4e38f;
            #pragma unroll
            for (int n = 0; n < 8; n++)
                #pragma unroll
                for (int jj = 0; jj < 4; jj++) mx = fmaxf(mx, acc[m][n][jj]);
            mx = fmaxf(mx, __shfl_xor(mx, 16));
            mx = fmaxf(mx, __shfl_xor(mx, 32));
            if (l < 16) red[m * 16 + rr][w] = mx;
        }
        __syncthreads();
        float gm[2];
        #pragma unroll
        for (int m = 0; m < 2; m++) {
            float g = red[m * 16 + rr][0];
            #pragma unroll
            for (int ww = 1; ww < 8; ww++) g = fmaxf(g, red[m * 16 + rr][ww]);
            gm[m] = g;
        }
        __syncthreads();
        #pragma unroll
        for (int m = 0; m < 2; m++) {
            float s = 0.f;
            #pragma unroll
            for (int n = 0; n < 8; n++)
                #pragma unroll
                for (int jj = 0; jj < 4; jj++) {
                    float p = __expf(acc[m][n][jj] - gm[m]);
                    acc[m][n][jj] = p;
                    s += p;
                }
            s += __shfl_xor(s, 16);
            s += __shfl_xor(s, 32);
            if (l < 16) red[m * 16 + rr][w] = s;
        }
        __syncthreads();
        #pragma unroll
        for (int m = 0; m < 2; m++) {
            float tot = 0.f;
            #pragma unroll
            for (int ww = 0; ww < 8; ww++) tot += red[m * 16 + rr][ww];
            float inv = 1.f / tot;
            int f = m * 16 + rr;                       // 0..31
            size_t rowg = (size_t)(b * 40 + f) * T_DIM + w * 128;
            #pragma unroll
            for (int n = 0; n < 8; n++) {
                f32x4 o;
                o.x = acc[m][n][0] * inv; o.y = acc[m][n][1] * inv;
                o.z = acc[m][n][2] * inv; o.w = acc[m][n][3] * inv;
                *(f32x4*)&A[rowg + n * 16 + q * 4] = o;
                uint2v pk;
                pk.x = (unsigned int)f2bf(lam * o.x + oml) | ((unsigned int)f2bf(lam * o.y + oml) << 16);
                pk.y = (unsigned int)f2bf(lam * o.z + oml) | ((unsigned int)f2bf(lam * o.w + oml) << 16);
                *(uint2v*)&gb[(size_t)(w * 2 + (n >> 2)) * 2560 + f * 64 + (n & 3) * 16 + q * 4] = pk;
            }
        }
        __syncthreads();                               // red reuse fence
    }
    {
        // ---- group B: rows b*40 + {32..39} (1 m-tile, rr<8 valid) ----
        int rowa = b * 40 + 32 + rr;
        int rowc = rowa < 20480 ? rowa : 20479;        // clamp (b=511, rr>=8)
        const float* xrowB = x + (size_t)rowc * T_DIM;
        f32x4 acc[8] = {};
        for (int ks = 0; ks < 32; ks++) {
            if (!((mask >> ks) & 1u)) continue;
            int off = ks * 32 + q * 8;
            bf16x8 bxB;
            MKFRAG(xrowB, off, bxB);
            const unsigned short* wp = wfrag + ((size_t)(w * 32 + ks) * 8) * 512 + (size_t)l * 8;
            #pragma unroll
            for (int n = 0; n < 8; n++) {
                bf16x8 af = *(const bf16x8*)(wp + (size_t)n * 512);
                acc[n] = __builtin_amdgcn_mfma_f32_16x16x32_bf16(af, bxB, acc[n], 0, 0, 0);
            }
        }
        float mx = -3.4e38f;
        #pragma unroll
        for (int n = 0; n < 8; n++)
            #pragma unroll
            for (int jj = 0; jj < 4; jj++) mx = fmaxf(mx, acc[n][jj]);
        mx = fmaxf(mx, __shfl_xor(mx, 16));
        mx = fmaxf(mx, __shfl_xor(mx, 32));
        if (l < 16) red[rr][w] = mx;
        __syncthreads();
        float g = red[rr][0];
        #pragma unroll
        for (int ww = 1; ww < 8; ww++) g = fmaxf(g, red[rr][ww]);
        __syncthreads();
        float s = 0.f;
        #pragma unroll
        for (int n = 0; n < 8; n++)
            #pragma unroll
            for (int jj = 0; jj < 4; jj++) {
                float p = __expf(acc[n][jj] - g);
                acc[n][jj] = p;
                s += p;
            }
        s += __shfl_xor(s, 16);
        s += __shfl_xor(s, 32);
        if (l < 16) red[rr][w] = s;
        __syncthreads();
        if (rr < 8) {
            float tot = 0.f;
            #pragma unroll
            for (int ww = 0; ww < 8; ww++) tot += red[rr][ww];
            float inv = 1.f / tot;
            int f = 32 + rr;
            size_t rowg = (size_t)(b * 40 + f) * T_DIM + w * 128;
            #pragma unroll
            for (int n = 0; n < 8; n++) {
                f32x4 o;
                o.x = acc[n][0] * inv; o.y = acc[n][1] * inv;
                o.z = acc[n][2] * inv; o.w = acc[n][3] * inv;
                *(f32x4*)&A[rowg + n * 16 + q * 4] = o;
                uint2v pk;
                pk.x = (unsigned int)f2bf(lam * o.x + oml) | ((unsigned int)f2bf(lam * o.y + oml) << 16);
                pk.y = (unsigned int)f2bf(lam * o.z + oml) | ((unsigned int)f2bf(lam * o.w + oml) << 16);
                *(uint2v*)&gb[(size_t)(w * 2 + (n >> 2)) * 2560 + f * 64 + (n & 3) * 16 + q * 4] = pk;
            }
        }
    }
    __syncthreads();   // all A + gate stores drained before phase 3 reads gb

    // ================= PHASE 3 (fused) =================
    bf16x8 aw[2];
    #pragma unroll
    for (int ks = 0; ks < 2; ks++)
        aw[ks] = *(const bf16x8*)(w1p + (w * 16 + rr) * 64 + ks * 32 + q * 8);
    int og = w * 16 + rr;              // lane's fixed o (strip row)
    int am = og % D1_IN;               // gate row
    int gofs = (am >> 3) * 528 + (am & 7) * 64;
    f32x4 acc2[4] = {};
    const float* xb = x + (size_t)b * D1_IN * T_DIM;

    auto STAGE_XG = [&](int buf, int tc) {
        int t0 = tc * 64;
        int f = w * 4 + (l >> 4);                 // group w: x rows 4w..4w+3
        gld16v(xb + (size_t)f * T_DIM + t0 + (l & 15) * 4, &xfst[buf][w * 260]);
        if (w < 2) {
            int f2 = 32 + w * 4 + (l >> 4);       // groups 8,9: rows 32..39
            gld16v(xb + (size_t)f2 * T_DIM + t0 + (l & 15) * 4, &xfst[buf][(8 + w) * 260]);
        }
        if (w < 5)                                 // gate: 5 sgroups of 8 rows
            gld16v(gb + (size_t)tc * 2560 + w * 512 + l * 8, &gs16[buf][w * 528]);
    };
    auto STAGE_W2 = [&](int tc) {
        gld16v(w2g + (size_t)tc * 4096 + w * 512 + l * 8, &w2s[w * 512]);
    };
    // CONVERT: one thread per (octet, t): 8 stride-64 word reads (2-way broadcast,
    // free) -> one b128 write at octet-XOR-swizzled slot (b128 bank floor).
    auto CONVERT = [&](int buf) {
        if (tid < 320) {
            int oct = tid >> 6, tt = tid & 63;
            const float* base = &xfst[buf][0];
            float v[8];
            #pragma unroll
            for (int i = 0; i < 8; i++) {
                int f = oct * 8 + i;
                v[i] = base[(f >> 2) * 260 + (f & 3) * 64 + tt];
            }
            uint4v pk;
            #pragma unroll
            for (int i = 0; i < 4; i++)
                pk[i] = (__float_as_uint(v[2 * i]) >> 16) | (__float_as_uint(v[2 * i + 1]) & 0xFFFF0000u);
            *(uint4v*)&xbt[tt * 72 + ((oct ^ ((tt >> 3) & 7)) << 3)] = pk;
        }
    };

    // zero ALL of xbt once: pad octets (swizzled slots never written) stay zero
    for (int i = tid; i < 2304; i += 512) ((unsigned int*)xbt)[i] = 0u;
    STAGE_XG(0, 0);
    __syncthreads();
    for (int tc = 0; tc < 16; tc++) {
        int cur = tc & 1;
        CONVERT(cur);
        STAGE_W2(tc);
        __syncthreads();                       // A: xbt + gs16 + w2s ready
        if (tc < 15) STAGE_XG(cur ^ 1, tc + 1);  // prefetch overlaps compute
        // X_bar^T via MFMA: frag read uses the same octet-XOR swizzle
        f32x4 acc1[4] = {};
        #pragma unroll
        for (int ni = 0; ni < 4; ni++) {
            int t = ni * 16 + rr;
            int sw = (t >> 3) & 7;
            #pragma unroll
            for (int ks = 0; ks < 2; ks++) {
                int oct = ks * 4 + q;
                bf16x8 bx = *(const bf16x8*)&xbt[t * 72 + ((oct ^ sw) << 3)];
                acc1[ni] = __builtin_amdgcn_mfma_f32_16x16x32_bf16(bx, aw[ks], acc1[ni], 0, 0, 0);
            }
        }
        // gate (bf16 LDS, pre-folded lam) + pack -> one ds_write_b64 per ni
        const unsigned short* gr = &gs16[cur][gofs];
        #pragma unroll
        for (int ni = 0; ni < 4; ni++) {
            uint2 gp = *(const uint2*)(gr + ni * 16 + q * 4);
            float e0 = acc1[ni][0] * bf2f(gp.x & 0xFFFFu);
            float e1 = acc1[ni][1] * bf2f(gp.x >> 16);
            float e2 = acc1[ni][2] * bf2f(gp.y & 0xFFFFu);
            float e3 = acc1[ni][3] * bf2f(gp.y >> 16);
            uint2 pk;
            pk.x = (unsigned int)f2bf(e0) | ((unsigned int)f2bf(e1) << 16);
            pk.y = (unsigned int)f2bf(e2) | ((unsigned int)f2bf(e3) << 16);
            *(uint2*)&xtl[og * 72 + ni * 16 + q * 4] = pk;
        }
        // GEMM2: a2 row = og (same-wave RAW on xtl), b2 from swizzled w2s LDS
        #pragma unroll
        for (int ks2 = 0; ks2 < 2; ks2++) {
            bf16x8 a2 = *(const bf16x8*)&xtl[og * 72 + ks2 * 32 + q * 8];
            #pragma unroll
            for (int ni = 0; ni < 4; ni++) {
                int s = ni * 16 + rr;
                bf16x8 b2 = *(const bf16x8*)&w2s[s * 64 + (((ks2 * 4 + q) ^ (s & 7)) << 3)];
                acc2[ni] = __builtin_amdgcn_mfma_f32_16x16x32_bf16(a2, b2, acc2[ni], 0, 0, 0);
            }
        }
        __syncthreads();                       // B: drains prefetch; protects buffers
    }
    #pragma unroll
    for (int ni = 0; ni < 4; ni++)
        #pragma unroll
        for (int j = 0; j < 4; j++) {
            int row = w * 16 + q * 4 + j;
            if (row < D1_OUT) {
                int col = ni * 16 + rr;
                float v = acc2[ni][j] + Bias[row * D2_OUT + col];
                out[((size_t)b * D1_OUT + row) * D2_OUT + col] = fmaxf(v, 0.f);
            }
        }
}

extern "C" void kernel_launch(void* const* d_in, const int* in_sizes, int n_in,
                              void* d_out, int out_size, void* d_ws, size_t ws_size,
                              hipStream_t stream) {
    const float* x    = (const float*)d_in[0];
    const float* W1   = (const float*)d_in[1];
    const float* W    = (const float*)d_in[2];
    const float* W2   = (const float*)d_in[3];
    const float* Bias = (const float*)d_in[4];
    const float* lam  = (const float*)d_in[5];
    float* out = (float*)d_out;
    float* A   = out + OUT0_SZ;                    // second output region

    char* ws = (char*)d_ws;
    unsigned short* gbuf  = (unsigned short*)(ws);              // 41,943,040 B
    unsigned short* wfrag = (unsigned short*)(ws + 41943040);   // 2 MB
    unsigned short* w2g   = (unsigned short*)(ws + 44040192);   // 128 KB
    unsigned short* w1p   = (unsigned short*)(ws + 44171264);   // 16 KB (total ~44.2 MB)

    hipLaunchKernelGGL(k_prep_small, dim3(73), dim3(256), 0, stream, W1, W, W2, w2g, w1p);
    hipLaunchKernelGGL(k_wfrag, dim3(256), dim3(256), 0, stream, W, wfrag);
    hipLaunchKernelGGL(k_mega, dim3(512), dim3(512), 0, stream, x, wfrag, w1p, w2g, Bias, lam, A, gbuf, out);
}